// Round 6
// baseline (216.731 us; speedup 1.0000x reference)
//
#include <hip/hip_runtime.h>

// Problem constants (B=8, Tq=Tv=512, D=512, U=128)
constexpr int Bb = 8;
constexpr int Tq = 512;
constexpr int Tv = 512;
constexpr int Dd = 512;
constexpr int Uu = 128;
constexpr float C2LOG2E = 2.88539008177792681f;   // 2*log2(e)
constexpr float LOG2E   = 1.44269504088896341f;

// ---------------------------------------------------------------------------
// Kernel A: projections, 8 rows/block, 256 threads, 1024 blocks (4/CU).
// Thread t: u = t&127, rg = t>>7 -> rows rg*4..rg*4+3. Explicit W prefetch.
//   q half -> qf2[row][u] (row-major), k half -> kT[b][u][j] (transposed).
// Both premultiplied by 2*log2e.
// ---------------------------------------------------------------------------
__global__ __launch_bounds__(256) void proj_kernel(
    const float* __restrict__ query,
    const float* __restrict__ key,
    const float* __restrict__ Wa,
    const float* __restrict__ Ua,
    float* __restrict__ qf2, float* __restrict__ kT)
{
    const int R    = blockIdx.x * 8;               // 0..8191
    const bool isQ = R < Bb * Tq;
    const float* __restrict__ src = isQ ? query : key;
    const float* __restrict__ W   = isQ ? Wa : Ua;
    const int Rloc = isQ ? R : R - Bb * Tq;        // 0..4095

    __shared__ float x[8 * Dd];                    // 16 KB
    const int t = threadIdx.x;

    {   // stage 8 rows: 1024 float4, 4 per thread, coalesced
        const float4* __restrict__ s4 =
            reinterpret_cast<const float4*>(src + (size_t)Rloc * Dd);
        float4* x4 = reinterpret_cast<float4*>(x);
#pragma unroll
        for (int m = 0; m < 4; ++m) x4[t + 256 * m] = s4[t + 256 * m];
    }
    __syncthreads();

    const int u  = t & 127;
    const int rg = t >> 7;                         // 0/1
    const float* __restrict__ Wu = W + u;
    float acc[4] = {0, 0, 0, 0};

    // software pipeline: W quad for d4+1 loads while d4 computes
    float wc0 = Wu[0 * Uu], wc1 = Wu[1 * Uu], wc2 = Wu[2 * Uu], wc3 = Wu[3 * Uu];
#pragma unroll 1
    for (int d4 = 0; d4 < Dd / 4; ++d4) {
        const int dn = (d4 + 1 < Dd / 4) ? (d4 + 1) * 4 : 0;
        const float wn0 = Wu[(size_t)(dn + 0) * Uu];
        const float wn1 = Wu[(size_t)(dn + 1) * Uu];
        const float wn2 = Wu[(size_t)(dn + 2) * Uu];
        const float wn3 = Wu[(size_t)(dn + 3) * Uu];
        const int d = d4 * 4;
#pragma unroll
        for (int k = 0; k < 4; ++k) {
            const float4 xv = *reinterpret_cast<const float4*>(x + (rg * 4 + k) * Dd + d);
            acc[k] = fmaf(xv.x, wc0, acc[k]);
            acc[k] = fmaf(xv.y, wc1, acc[k]);
            acc[k] = fmaf(xv.z, wc2, acc[k]);
            acc[k] = fmaf(xv.w, wc3, acc[k]);
        }
        wc0 = wn0; wc1 = wn1; wc2 = wn2; wc3 = wn3;
    }

    if (isQ) {
#pragma unroll
        for (int k = 0; k < 4; ++k)
            qf2[(size_t)(Rloc + rg * 4 + k) * Uu + u] = C2LOG2E * acc[k];
    } else {
        const int b  = Rloc >> 9;
        const int j0 = (Rloc & 511) + rg * 4;
        float4 o;
        o.x = C2LOG2E * acc[0]; o.y = C2LOG2E * acc[1];
        o.z = C2LOG2E * acc[2]; o.w = C2LOG2E * acc[3];
        *reinterpret_cast<float4*>(kT + (size_t)b * Uu * Tv + (size_t)u * Tv + j0) = o;
    }
}

// ---------------------------------------------------------------------------
// Kernel B: attention, 8 query rows/block, 512 threads, thread t <-> key j=t.
//   score_i(j) = S + sum_u s2_u * rcp(1 + exp2(q2[i][u] + kT[u][j]))
// Explicit k prefetch in score loop, value prefetch in context loop.
// ---------------------------------------------------------------------------
__global__ __launch_bounds__(512) void attn_kernel(
    const float* __restrict__ qf2, const float* __restrict__ kT,
    const float* __restrict__ value,
    const int* __restrict__ mask,
    const float* __restrict__ scale,
    float* __restrict__ out)
{
    const int r0 = blockIdx.x * 8;            // first query row (0..4095)
    const int b  = r0 >> 9;
    const int t  = threadIdx.x;               // 0..511

    __shared__ float q2[8 * Uu];              // 4 KB
    __shared__ float s2[Uu];
    __shared__ float w[8 * Tv];               // 16 KB
    __shared__ float inv8[8];
    __shared__ float Ssum;

    const int j  = t;
    const int mk = mask[b * Tv + j];          // hoisted early

    if (t < 256)
        reinterpret_cast<float4*>(q2)[t] =
            reinterpret_cast<const float4*>(qf2 + (size_t)r0 * Uu)[t];
    if (t >= 256 && t < 384) { const int u = t - 256; s2[u] = -2.f * scale[u]; }
    if (t < 64) {
        float v = scale[t] + scale[t + 64];
#pragma unroll
        for (int off = 32; off; off >>= 1) v += __shfl_xor(v, off, 64);
        if (t == 0) Ssum = v;
    }
    __syncthreads();

    // ---- scores (software-pipelined k loads) ----
    const float* __restrict__ kb = kT + (size_t)b * Uu * Tv + j;
    float acc[8] = {0,0,0,0,0,0,0,0};
    float4 kc, kn;
    kc.x = kb[0 * (size_t)Tv]; kc.y = kb[1 * (size_t)Tv];
    kc.z = kb[2 * (size_t)Tv]; kc.w = kb[3 * (size_t)Tv];
#pragma unroll 1
    for (int u4 = 0; u4 < Uu / 4; ++u4) {
        const int nb = (u4 + 1 < Uu / 4) ? (u4 + 1) * 4 : 0;
        kn.x = kb[(size_t)(nb + 0) * Tv];
        kn.y = kb[(size_t)(nb + 1) * Tv];
        kn.z = kb[(size_t)(nb + 2) * Tv];
        kn.w = kb[(size_t)(nb + 3) * Tv];
        const float4 sv = reinterpret_cast<const float4*>(s2)[u4];
#pragma unroll
        for (int i = 0; i < 8; ++i) {
            const float4 qv = *reinterpret_cast<const float4*>(q2 + i * Uu + u4 * 4);
            float e0 = __builtin_amdgcn_exp2f(qv.x + kc.x);
            float e1 = __builtin_amdgcn_exp2f(qv.y + kc.y);
            float e2 = __builtin_amdgcn_exp2f(qv.z + kc.z);
            float e3 = __builtin_amdgcn_exp2f(qv.w + kc.w);
            acc[i] = fmaf(sv.x, __builtin_amdgcn_rcpf(e0 + 1.f), acc[i]);
            acc[i] = fmaf(sv.y, __builtin_amdgcn_rcpf(e1 + 1.f), acc[i]);
            acc[i] = fmaf(sv.z, __builtin_amdgcn_rcpf(e2 + 1.f), acc[i]);
            acc[i] = fmaf(sv.w, __builtin_amdgcn_rcpf(e3 + 1.f), acc[i]);
        }
        kc = kn;
    }
    {
        const float S = Ssum;
#pragma unroll
        for (int i = 0; i < 8; ++i)
            w[i * Tv + j] = mk ? (S + acc[i]) : -1e9f;
    }
    __syncthreads();

    // ---- softmax: wave wv handles row wv ----
    {
        const int wv = t >> 6, ln = t & 63;
        float* __restrict__ row = w + wv * Tv;
        float vals[8];
        float m = -3e38f;
#pragma unroll
        for (int c = 0; c < 8; ++c) { vals[c] = row[ln + 64 * c]; m = fmaxf(m, vals[c]); }
#pragma unroll
        for (int off = 32; off; off >>= 1) m = fmaxf(m, __shfl_xor(m, off, 64));
        float sum = 0.f;
#pragma unroll
        for (int c = 0; c < 8; ++c) {
            float e = __builtin_amdgcn_exp2f((vals[c] - m) * LOG2E);
            row[ln + 64 * c] = e;
            sum += e;
        }
#pragma unroll
        for (int off = 32; off; off >>= 1) sum += __shfl_xor(sum, off, 64);
        if (ln == 0) inv8[wv] = 1.0f / sum;
    }
    __syncthreads();

    // ---- context (software-pipelined value loads) ----
    const int ti = t >> 7;                 // 0..3
    const int td = t & 127;
    const int d0 = td * 4;
    const int i0 = ti, i1 = ti + 4;
    const float* __restrict__ vb = value + (size_t)b * Tv * Dd + d0;
    float4 a0 = {0,0,0,0}, a1 = {0,0,0,0};
    float4 v0c = *reinterpret_cast<const float4*>(vb + 0 * (size_t)Dd);
    float4 v1c = *reinterpret_cast<const float4*>(vb + 1 * (size_t)Dd);
    float4 v2c = *reinterpret_cast<const float4*>(vb + 2 * (size_t)Dd);
    float4 v3c = *reinterpret_cast<const float4*>(vb + 3 * (size_t)Dd);
#pragma unroll 1
    for (int j4 = 0; j4 < Tv / 4; ++j4) {
        const int jn = (j4 + 1 < Tv / 4) ? (j4 + 1) * 4 : 0;
        const float4 v0n = *reinterpret_cast<const float4*>(vb + (size_t)(jn + 0) * Dd);
        const float4 v1n = *reinterpret_cast<const float4*>(vb + (size_t)(jn + 1) * Dd);
        const float4 v2n = *reinterpret_cast<const float4*>(vb + (size_t)(jn + 2) * Dd);
        const float4 v3n = *reinterpret_cast<const float4*>(vb + (size_t)(jn + 3) * Dd);
        const float4 w0 = *reinterpret_cast<const float4*>(w + i0 * Tv + j4 * 4);
        const float4 w1 = *reinterpret_cast<const float4*>(w + i1 * Tv + j4 * 4);
        a0.x = fmaf(w0.x, v0c.x, a0.x); a0.y = fmaf(w0.x, v0c.y, a0.y);
        a0.z = fmaf(w0.x, v0c.z, a0.z); a0.w = fmaf(w0.x, v0c.w, a0.w);
        a1.x = fmaf(w1.x, v0c.x, a1.x); a1.y = fmaf(w1.x, v0c.y, a1.y);
        a1.z = fmaf(w1.x, v0c.z, a1.z); a1.w = fmaf(w1.x, v0c.w, a1.w);
        a0.x = fmaf(w0.y, v1c.x, a0.x); a0.y = fmaf(w0.y, v1c.y, a0.y);
        a0.z = fmaf(w0.y, v1c.z, a0.z); a0.w = fmaf(w0.y, v1c.w, a0.w);
        a1.x = fmaf(w1.y, v1c.x, a1.x); a1.y = fmaf(w1.y, v1c.y, a1.y);
        a1.z = fmaf(w1.y, v1c.z, a1.z); a1.w = fmaf(w1.y, v1c.w, a1.w);
        a0.x = fmaf(w0.z, v2c.x, a0.x); a0.y = fmaf(w0.z, v2c.y, a0.y);
        a0.z = fmaf(w0.z, v2c.z, a0.z); a0.w = fmaf(w0.z, v2c.w, a0.w);
        a1.x = fmaf(w1.z, v2c.x, a1.x); a1.y = fmaf(w1.z, v2c.y, a1.y);
        a1.z = fmaf(w1.z, v2c.z, a1.z); a1.w = fmaf(w1.z, v2c.w, a1.w);
        a0.x = fmaf(w0.w, v3c.x, a0.x); a0.y = fmaf(w0.w, v3c.y, a0.y);
        a0.z = fmaf(w0.w, v3c.z, a0.z); a0.w = fmaf(w0.w, v3c.w, a0.w);
        a1.x = fmaf(w1.w, v3c.x, a1.x); a1.y = fmaf(w1.w, v3c.y, a1.y);
        a1.z = fmaf(w1.w, v3c.z, a1.z); a1.w = fmaf(w1.w, v3c.w, a1.w);
        v0c = v0n; v1c = v1n; v2c = v2n; v3c = v3n;
    }
    const float iv0 = inv8[i0], iv1 = inv8[i1];
    float4 o0, o1;
    o0.x = a0.x * iv0; o0.y = a0.y * iv0; o0.z = a0.z * iv0; o0.w = a0.w * iv0;
    o1.x = a1.x * iv1; o1.y = a1.y * iv1; o1.z = a1.z * iv1; o1.w = a1.w * iv1;
    *reinterpret_cast<float4*>(out + (size_t)(r0 + i0) * Dd + d0) = o0;
    *reinterpret_cast<float4*>(out + (size_t)(r0 + i1) * Dd + d0) = o1;
}

extern "C" void kernel_launch(void* const* d_in, const int* in_sizes, int n_in,
                              void* d_out, int out_size, void* d_ws, size_t ws_size,
                              hipStream_t stream)
{
    const float* query = (const float*)d_in[0];
    const float* key   = (const float*)d_in[1];
    const float* value = (const float*)d_in[2];
    const int*   mask  = (const int*)d_in[3];     // proven int32 (R2 bit-identical)
    const float* Wa    = (const float*)d_in[4];
    const float* Ua    = (const float*)d_in[5];
    const float* scale = (const float*)d_in[6];
    float* out = (float*)d_out;

    float* qf2 = (float*)d_ws;                    // [4096,128] = 2 MB (premult)
    float* kT  = qf2 + Bb * Tq * Uu;              // [8][128][512] = 2 MB (premult, transposed)

    proj_kernel<<<(2 * Bb * Tq) / 8, 256, 0, stream>>>(query, key, Wa, Ua, qf2, kT);
    attn_kernel<<<(Bb * Tq) / 8, 512, 0, stream>>>(qf2, kT, value, mask, scale, out);
}